// Round 6
// baseline (580.817 us; speedup 1.0000x reference)
//
#include <hip/hip_runtime.h>
#include <cstdint>
#include <cstddef>

#define T_TOK 4096
#define DIM   1024
#define NEXP  8
#define HDIM  4096
#define NSLOT (2 * T_TOK)

#define BM 128
#define BN1 128   // gemm1 h-cols per block (dual-B)
#define BN2 256   // gemm2 out-cols per block
#define BK 32

typedef __attribute__((ext_vector_type(8))) short s16x8;
typedef __attribute__((ext_vector_type(4))) float f32x4;

__device__ __forceinline__ unsigned short f2bf(float f) {
    union { float f; unsigned u; } v; v.f = f;
    unsigned u = v.u;
    unsigned r = (u + 0x7FFFu + ((u >> 16) & 1u)) >> 16;  // RNE
    return (unsigned short)r;
}

// element offset into a [row][32] bf16 tile, 16B-chunk XOR swizzle:
// slot c of row holds global chunk c ^ ((row>>1)&3)
__device__ __forceinline__ int lds_off(int row, int kchunk) {
    return row * 32 + ((kchunk ^ ((row >> 1) & 3)) << 3);
}

// async global->LDS, 16B per lane; LDS dest wave-uniform base + lane*16.
__device__ __forceinline__ void gload16(const void* g, void* l) {
    __builtin_amdgcn_global_load_lds(
        (const __attribute__((address_space(1))) unsigned int*)g,
        (__attribute__((address_space(3))) unsigned int*)l, 16, 0, 0);
}

// ------- gating: fp32 logits, top-2 + write token-ordered bf16 xg ----------
__global__ __launch_bounds__(256) void gate_kernel(
    const float* __restrict__ x, const float* __restrict__ wg,
    int* __restrict__ tok_e, float* __restrict__ tok_w, int* __restrict__ counts,
    unsigned short* __restrict__ xg)
{
    int t = blockIdx.x * 4 + (threadIdx.x >> 6);
    int lane = threadIdx.x & 63;
    float acc[NEXP];
#pragma unroll
    for (int e = 0; e < NEXP; ++e) acc[e] = 0.f;
    const float* xrow = x + (size_t)t * DIM;
    unsigned short* xgrow = xg + (size_t)t * DIM;
    for (int d = lane; d < DIM; d += 64) {
        float xv = xrow[d];
        xgrow[d] = f2bf(xv);
        const float4* wr = (const float4*)(wg + (size_t)d * NEXP);
        float4 w0 = wr[0], w1v = wr[1];
        acc[0] += xv * w0.x;  acc[1] += xv * w0.y;
        acc[2] += xv * w0.z;  acc[3] += xv * w0.w;
        acc[4] += xv * w1v.x; acc[5] += xv * w1v.y;
        acc[6] += xv * w1v.z; acc[7] += xv * w1v.w;
    }
#pragma unroll
    for (int e = 0; e < NEXP; ++e)
#pragma unroll
        for (int off = 32; off > 0; off >>= 1)
            acc[e] += __shfl_xor(acc[e], off);
    if (lane == 0) {
        int i0 = 0;
#pragma unroll
        for (int e = 1; e < NEXP; ++e) if (acc[e] > acc[i0]) i0 = e;
        int i1 = (i0 == 0) ? 1 : 0;
#pragma unroll
        for (int e = 0; e < NEXP; ++e) if (e != i0 && acc[e] > acc[i1]) i1 = e;
        float w0 = 1.f / (1.f + __expf(acc[i1] - acc[i0]));
        tok_e[2 * t] = i0;  tok_e[2 * t + 1] = i1;
        tok_w[2 * t] = w0;  tok_w[2 * t + 1] = 1.f - w0;
        atomicAdd(&counts[i0], 1);
        atomicAdd(&counts[i1], 1);
    }
}

__global__ void scan_kernel(const int* __restrict__ counts,
                            int* __restrict__ offsets, int* __restrict__ cursor)
{
    if (threadIdx.x == 0) {
        int s = 0;
        for (int e = 0; e < NEXP; ++e) { offsets[e] = s; s += counts[e]; cursor[e] = 0; }
        offsets[NEXP] = s;
    }
}

__global__ __launch_bounds__(256) void assign_kernel(
    const int* __restrict__ tok_e, const float* __restrict__ tok_w,
    const int* __restrict__ offsets, int* __restrict__ cursor,
    int* __restrict__ rows_tok, float* __restrict__ rows_gate)
{
    int t = blockIdx.x * 256 + threadIdx.x;
    if (t >= T_TOK) return;
#pragma unroll
    for (int j = 0; j < 2; ++j) {
        int e = tok_e[2 * t + j];
        int pos = offsets[e] + atomicAdd(&cursor[e], 1);
        rows_tok[pos] = t;
        rows_gate[pos] = tok_w[2 * t + j];
    }
}

// ------------- transpose+convert: src [E][R][C] f32 -> dst [E][C][R] bf16 ---
// 64x64 tile via LDS ([64c][33] u32 pad layout, <=2-way conflicts).
__device__ __forceinline__ void tconv_body(
    const float* __restrict__ src, unsigned short* __restrict__ dst,
    int R, int C, int e, int bx, int by, int t)
{
    __shared__ unsigned int t_lds[64 * 33];
    int c0 = bx * 64, r0 = by * 64;
    int lane = t & 63, w = t >> 6;
    const float* s = src + (size_t)e * R * C + (size_t)(r0 + w * 16) * C + c0 + lane;
#pragma unroll
    for (int j = 0; j < 8; ++j) {
        float v0 = s[(size_t)(2 * j) * C];
        float v1 = s[(size_t)(2 * j + 1) * C];
        unsigned int pk = (unsigned int)f2bf(v0) | ((unsigned int)f2bf(v1) << 16);
        t_lds[lane * 33 + (w * 8 + j)] = pk;
    }
    __syncthreads();
    unsigned short* dbase = dst + (size_t)e * C * R;
#pragma unroll
    for (int rep = 0; rep < 2; ++rep) {
        int idx = rep * 256 + t;
        int c = idx >> 3, chunk = idx & 7;
        uint4 o;
        o.x = t_lds[c * 33 + chunk * 4 + 0];
        o.y = t_lds[c * 33 + chunk * 4 + 1];
        o.z = t_lds[c * 33 + chunk * 4 + 2];
        o.w = t_lds[c * 33 + chunk * 4 + 3];
        *(uint4*)(dbase + (size_t)(c0 + c) * R + r0 + chunk * 8) = o;
    }
}

// fused w1+w3 transpose (z<8 -> w1, else w3)
__global__ __launch_bounds__(256) void tconv13_kernel(
    const float* __restrict__ w1, const float* __restrict__ w3,
    unsigned short* __restrict__ w1t, unsigned short* __restrict__ w3t)
{
    int z = blockIdx.z;
    if (z < NEXP)
        tconv_body(w1, w1t, DIM, HDIM, z, blockIdx.x, blockIdx.y, threadIdx.x);
    else
        tconv_body(w3, w3t, DIM, HDIM, z - NEXP, blockIdx.x, blockIdx.y, threadIdx.x);
}

__global__ __launch_bounds__(256) void tconv_kernel(
    const float* __restrict__ src, unsigned short* __restrict__ dst, int R, int C)
{
    tconv_body(src, dst, R, C, blockIdx.z, blockIdx.x, blockIdx.y, threadIdx.x);
}

// ---------------- GEMM1: h = silu(xg@w1) * (xg@w3), grouped by expert ------
// 512 thr / 8 waves (2Mx4N), wave 64x32 per B-matrix (64x64 effective).
// A gathered from token-ordered xg via toks[] (per-lane global src for
// global_load_lds is allowed; LDS dest stays wave-uniform linear).
__global__ __launch_bounds__(512, 4) void gemm1_kernel(
    const unsigned short* __restrict__ xg,
    const unsigned short* __restrict__ w1t, const unsigned short* __restrict__ w3t,
    const int* __restrict__ rows_tok, const int* __restrict__ offsets,
    unsigned short* __restrict__ h)
{
    int e = blockIdx.z;
    int offs = offsets[e];
    int cnt  = offsets[e + 1] - offs;
    int m0 = blockIdx.y * BM;
    if (m0 >= cnt) return;
    int n0 = blockIdx.x * BN1;

    __shared__ unsigned short As[2][BM * BK];
    __shared__ unsigned short B1s[2][BN1 * BK];
    __shared__ unsigned short B3s[2][BN1 * BK];
    __shared__ int toks[BM];

    int tid = threadIdx.x;
    if (tid < BM) toks[tid] = rows_tok[offs + min(m0 + tid, cnt - 1)];
    __syncthreads();

    int lane = tid & 63;
    int wid = tid >> 6;
    int wr = wid >> 2, wc = wid & 3;
    int lr = lane & 15, lg = lane >> 4;

    int srow = tid >> 2;
    int g = (tid & 3) ^ ((srow >> 1) & 3);
    const unsigned short* asrc  = xg  + (size_t)toks[srow] * DIM + g * 8;
    const unsigned short* b1src = w1t + ((size_t)e * HDIM + n0 + srow) * DIM + g * 8;
    const unsigned short* b3src = w3t + ((size_t)e * HDIM + n0 + srow) * DIM + g * 8;
    int ldsbase = wid * 512;

    f32x4 acc1[4][2] = {};
    f32x4 acc3[4][2] = {};

    auto stage = [&](int buf, int k0) {
        gload16(asrc + k0,  &As[buf][ldsbase]);
        gload16(b1src + k0, &B1s[buf][ldsbase]);
        gload16(b3src + k0, &B3s[buf][ldsbase]);
    };

    auto compute = [&](int buf) {
        s16x8 a[4];
#pragma unroll
        for (int m = 0; m < 4; ++m)
            a[m] = *(const s16x8*)&As[buf][lds_off(wr * 64 + m * 16 + lr, lg)];
#pragma unroll
        for (int n = 0; n < 2; ++n) {
            int rowb = wc * 32 + n * 16 + lr;
            s16x8 b1f = *(const s16x8*)&B1s[buf][lds_off(rowb, lg)];
            s16x8 b3f = *(const s16x8*)&B3s[buf][lds_off(rowb, lg)];
#pragma unroll
            for (int m = 0; m < 4; ++m)
                acc1[m][n] = __builtin_amdgcn_mfma_f32_16x16x32_bf16(a[m], b1f, acc1[m][n], 0, 0, 0);
#pragma unroll
            for (int m = 0; m < 4; ++m)
                acc3[m][n] = __builtin_amdgcn_mfma_f32_16x16x32_bf16(a[m], b3f, acc3[m][n], 0, 0, 0);
        }
    };

    stage(0, 0);
    __syncthreads();
    int buf = 0;
    for (int kt = 1; kt < DIM / BK; ++kt) {
        stage(buf ^ 1, kt * BK);
        compute(buf);
        __syncthreads();
        buf ^= 1;
    }
    compute(buf);

#pragma unroll
    for (int m = 0; m < 4; ++m)
#pragma unroll
        for (int n = 0; n < 2; ++n)
#pragma unroll
            for (int r = 0; r < 4; ++r) {
                int row_local = wr * 64 + m * 16 + lg * 4 + r;
                if (m0 + row_local < cnt) {
                    int col_local = wc * 32 + n * 16 + lr;
                    float g1 = acc1[m][n][r];
                    float hv = (g1 / (1.f + __expf(-g1))) * acc3[m][n][r];
                    h[(size_t)(offs + m0 + row_local) * HDIM + n0 + col_local] = f2bf(hv);
                }
            }
}

// -------- GEMM2: out[tok] += gate * (h @ w2); 128x256 block, 64x64 wave ----
// Exactly 2 atomic contributions per out element (commutative fp32 add)
// -> bitwise deterministic across replays.
__global__ __launch_bounds__(512, 4) void gemm2_kernel(
    const unsigned short* __restrict__ h, const unsigned short* __restrict__ w2t,
    const int* __restrict__ rows_tok, const float* __restrict__ rows_gate,
    const int* __restrict__ offsets, float* __restrict__ out)
{
    int e = blockIdx.z;
    int offs = offsets[e];
    int cnt  = offsets[e + 1] - offs;
    int m0 = blockIdx.y * BM;
    if (m0 >= cnt) return;
    int n0 = blockIdx.x * BN2;   // over DIM

    __shared__ unsigned short As[2][BM * BK];   // 16 KB
    __shared__ unsigned short Bs[2][BN2 * BK];  // 32 KB
    __shared__ int   toks[BM];
    __shared__ float gts[BM];

    int tid = threadIdx.x;
    if (tid < BM) {
        int p = offs + min(m0 + tid, cnt - 1);
        toks[tid] = rows_tok[p];
        gts[tid]  = rows_gate[p];
    }

    int lane = tid & 63;
    int wid = tid >> 6;
    int wr = wid >> 2, wc = wid & 3;   // 2M x 4N, wave tile 64x64
    int lr = lane & 15, lg = lane >> 4;

    int srow = tid >> 2;               // 0..127
    int g = (tid & 3) ^ ((srow >> 1) & 3);
    int arow = offs + min(m0 + srow, cnt - 1);
    const unsigned short* asrc = h + (size_t)arow * HDIM + g * 8;
    const unsigned short* bsrc0 = w2t + ((size_t)e * DIM + n0 + srow) * HDIM + g * 8;
    const unsigned short* bsrc1 = w2t + ((size_t)e * DIM + n0 + 128 + srow) * HDIM + g * 8;
    int ldsA = wid * 512;

    f32x4 acc[4][4] = {};

    auto stage = [&](int buf, int k0) {
        gload16(asrc + k0,  &As[buf][ldsA]);
        gload16(bsrc0 + k0, &Bs[buf][ldsA]);
        gload16(bsrc1 + k0, &Bs[buf][4096 + ldsA]);
    };

    auto compute = [&](int buf) {
        s16x8 a[4];
#pragma unroll
        for (int m = 0; m < 4; ++m)
            a[m] = *(const s16x8*)&As[buf][lds_off(wr * 64 + m * 16 + lr, lg)];
#pragma unroll
        for (int n = 0; n < 4; ++n) {
            s16x8 bf = *(const s16x8*)&Bs[buf][lds_off(wc * 64 + n * 16 + lr, lg)];
#pragma unroll
            for (int m = 0; m < 4; ++m)
                acc[m][n] = __builtin_amdgcn_mfma_f32_16x16x32_bf16(a[m], bf, acc[m][n], 0, 0, 0);
        }
    };

    __syncthreads();   // toks/gts ready (also orders first stage writes)
    stage(0, 0);
    __syncthreads();
    int buf = 0;
    for (int kt = 1; kt < HDIM / BK; ++kt) {
        stage(buf ^ 1, kt * BK);
        compute(buf);
        __syncthreads();
        buf ^= 1;
    }
    compute(buf);

#pragma unroll
    for (int m = 0; m < 4; ++m)
#pragma unroll
        for (int n = 0; n < 4; ++n)
#pragma unroll
            for (int r = 0; r < 4; ++r) {
                int row_local = wr * 64 + m * 16 + lg * 4 + r;
                if (m0 + row_local < cnt) {
                    int col = n0 + wc * 64 + n * 16 + lr;
                    float v = acc[m][n][r] * gts[row_local];
                    atomicAdd(&out[(size_t)toks[row_local] * DIM + col], v);
                }
            }
}

// ---------------------------------------------------------------------------
extern "C" void kernel_launch(void* const* d_in, const int* in_sizes, int n_in,
                              void* d_out, int out_size, void* d_ws, size_t ws_size,
                              hipStream_t stream)
{
    const float* x  = (const float*)d_in[0];
    const float* wg = (const float*)d_in[1];
    const float* w1 = (const float*)d_in[2];
    const float* w3 = (const float*)d_in[3];
    const float* w2 = (const float*)d_in[4];
    float* out = (float*)d_out;

    // Workspace ~200.2 MiB. Alias: w2t<-w1t (w1t dead after gemm1).
    char* ws = (char*)d_ws;
    size_t off = 0;
    auto alloc = [&](size_t bytes) -> void* {
        void* p = ws + off;
        off = (off + bytes + 255) & ~(size_t)255;
        return p;
    };
    int*   rows_tok  = (int*)alloc((size_t)NSLOT * 4);
    float* rows_gate = (float*)alloc((size_t)NSLOT * 4);
    int*   tok_e     = (int*)alloc((size_t)NSLOT * 4);
    float* tok_w     = (float*)alloc((size_t)NSLOT * 4);
    int*   counts    = (int*)alloc(NEXP * 4);
    int*   offsets   = (int*)alloc((NEXP + 1) * 4);
    int*   cursor    = (int*)alloc(NEXP * 4);
    unsigned short* xg   = (unsigned short*)alloc((size_t)T_TOK * DIM * 2);       // 8 MiB (token order)
    unsigned short* w1t  = (unsigned short*)alloc((size_t)NEXP * HDIM * DIM * 2); // 64 MiB
    unsigned short* w3t  = (unsigned short*)alloc((size_t)NEXP * HDIM * DIM * 2); // 64 MiB
    unsigned short* hbuf = (unsigned short*)alloc((size_t)NSLOT * HDIM * 2);      // 64 MiB
    unsigned short* w2t  = w1t;   // alias: dead after gemm1

    hipMemsetAsync(counts, 0, NEXP * 4, stream);
    hipMemsetAsync(out, 0, (size_t)out_size * sizeof(float), stream);

    gate_kernel<<<T_TOK / 4, 256, 0, stream>>>(x, wg, tok_e, tok_w, counts, xg);
    scan_kernel<<<1, 64, 0, stream>>>(counts, offsets, cursor);
    assign_kernel<<<T_TOK / 256, 256, 0, stream>>>(tok_e, tok_w, offsets, cursor,
                                                   rows_tok, rows_gate);

    // w1,w3: [E][D][H] -> [E][H][D] in one dispatch
    tconv13_kernel<<<dim3(HDIM / 64, DIM / 64, 2 * NEXP), 256, 0, stream>>>(
        w1, w3, w1t, w3t);

    gemm1_kernel<<<dim3(HDIM / BN1, T_TOK / BM, NEXP), 512, 0, stream>>>(
        xg, w1t, w3t, rows_tok, offsets, hbuf);

    // w2: [E][H][D] -> [E][D][H]  (into w1t's region, now dead)
    tconv_kernel<<<dim3(DIM / 64, HDIM / 64, NEXP), 256, 0, stream>>>(w2, w2t, HDIM, DIM);

    gemm2_kernel<<<dim3(DIM / BN2, T_TOK / BM, NEXP), 512, 0, stream>>>(
        hbuf, w2t, rows_tok, rows_gate, offsets, out);
}